// Round 3
// baseline (413.633 us; speedup 1.0000x reference)
//
#include <hip/hip_runtime.h>

#define N_CELL 200000
#define N_WELL 2000
#define E_CC   1200000
#define E_CW   200000
#define CF     16
#define WF     8
#define H      128
#define OUTF   75

#define NBLK_C 196          // ceil(200000/1024)
#define WACC_S 40           // per-well accumulator stride (floats)

__device__ __forceinline__ float b2f(unsigned short u) {
    union { unsigned int i; float f; } v; v.i = ((unsigned int)u) << 16; return v.f;
}
__device__ __forceinline__ unsigned short f2b(float f) {
    union { float f; unsigned int i; } v; v.f = f;
    unsigned int i = v.i;
    return (unsigned short)((i + 0x7fffu + ((i >> 16) & 1u)) >> 16);  // RNE
}
__device__ __forceinline__ float lo16(unsigned int v) { return b2f((unsigned short)(v & 0xffffu)); }
__device__ __forceinline__ float hi16(unsigned int v) { return b2f((unsigned short)(v >> 16)); }

// dtype-flexible scalar load: bf==1 -> bf16 array, bf==0 -> f32 array
__device__ __forceinline__ float ldf(const void* p, int i, int bf) {
    return bf ? b2f(((const unsigned short*)p)[i]) : ((const float*)p)[i];
}

// ---- dtype sniff: bf16-pair low halves have bf16-like exponents; f32 mantissa-low words are uniform
__global__ __launch_bounds__(256) void k_sniff(const unsigned int* __restrict__ x, int* __restrict__ flag)
{
    __shared__ int cnt[256];
    int t = threadIdx.x;
    unsigned int d = x[t];
    unsigned int e = (d >> 7) & 0xffu;           // exponent field of the low 16 bits viewed as bf16
    cnt[t] = (e >= 110u && e <= 135u) ? 1 : 0;
    __syncthreads();
    for (int o = 128; o > 0; o >>= 1) { if (t < o) cnt[t] += cnt[t + o]; __syncthreads(); }
    if (t == 0) flag[0] = (cnt[0] >= 192) ? 1 : 0;   // 1 = bf16, 0 = f32
}

// ---- fused weight products (f32):
// G1 = W_cell@Wl_cc [16,128], G2 = W_cell@Wr_cc [16,128]
// g1 = b_cell@Wl_cc [128],    g2 = b_cell@Wr_cc + bl_cc [128]
__global__ __launch_bounds__(128) void k_precomp(const void* __restrict__ W_cell,
                                                 const void* __restrict__ b_cell,
                                                 const void* __restrict__ Wl,
                                                 const void* __restrict__ Wr,
                                                 const void* __restrict__ bl,
                                                 const int* __restrict__ flag,
                                                 float* __restrict__ G1, float* __restrict__ G2,
                                                 float* __restrict__ g1v, float* __restrict__ g2v)
{
    int f = threadIdx.x, b = blockIdx.x, bf = flag[0];
    if (b < 16) {
        float s1 = 0.f, s2 = 0.f;
        for (int j = 0; j < H; ++j) {
            float wc = ldf(W_cell, b * H + j, bf);
            s1 += wc * ldf(Wl, j * H + f, bf);
            s2 += wc * ldf(Wr, j * H + f, bf);
        }
        G1[b * H + f] = s1; G2[b * H + f] = s2;
    } else {
        float s1 = 0.f, s2 = 0.f;
        for (int j = 0; j < H; ++j) {
            float bc = ldf(b_cell, j, bf);
            s1 += bc * ldf(Wl, j * H + f, bf);
            s2 += bc * ldf(Wr, j * H + f, bf);
        }
        g1v[f] = s1; g2v[f] = s2 + ldf(bl, f, bf);
    }
}

// ---- cell CSR build ----
__global__ void k_count(const int* __restrict__ dst, int* __restrict__ counts)
{
    int i = blockIdx.x * 256 + threadIdx.x;
    if (i < E_CC) {
        unsigned d = (unsigned)dst[i];
        if (d < N_CELL) atomicAdd(&counts[d], 1);
    }
}

__global__ __launch_bounds__(1024) void k_scan1(const int* __restrict__ counts,
                                                int* __restrict__ incl, int* __restrict__ bs)
{
    __shared__ int sm[1024];
    int t = threadIdx.x, i = blockIdx.x * 1024 + t;
    sm[t] = (i < N_CELL) ? counts[i] : 0;
    __syncthreads();
    for (int off = 1; off < 1024; off <<= 1) {
        int u = (t >= off) ? sm[t - off] : 0;
        __syncthreads();
        sm[t] += u;
        __syncthreads();
    }
    incl[i] = sm[t];
    if (t == 1023) bs[blockIdx.x] = sm[1023];
}

__global__ __launch_bounds__(256) void k_scan2(int* __restrict__ bs)
{
    __shared__ int sm[256];
    int t = threadIdx.x;
    sm[t] = (t < NBLK_C) ? bs[t] : 0;
    __syncthreads();
    for (int off = 1; off < 256; off <<= 1) {
        int u = (t >= off) ? sm[t - off] : 0;
        __syncthreads();
        sm[t] += u;
        __syncthreads();
    }
    if (t < NBLK_C) bs[t] = sm[t];
}

__global__ __launch_bounds__(1024) void k_scan3(const int* __restrict__ incl, const int* __restrict__ bs,
                                                int* __restrict__ offs, int* __restrict__ curs)
{
    int b = blockIdx.x, t = threadIdx.x, i = b * 1024 + t;
    if (i >= N_CELL) return;
    int v = incl[i] + (b ? bs[b - 1] : 0);
    offs[i + 1] = v; curs[i + 1] = v;
    if (i == 0) { offs[0] = 0; curs[0] = 0; }
}

__global__ void k_fill(const int* __restrict__ src, const int* __restrict__ dst,
                       int* __restrict__ curs, int* __restrict__ sorted)
{
    int i = blockIdx.x * 256 + threadIdx.x;
    if (i < E_CC) {
        unsigned d = (unsigned)dst[i];
        if (d < N_CELL) {
            int p = atomicAdd(&curs[d], 1);
            if ((unsigned)p < E_CC) sorted[p] = src[i];
        }
    }
}

// ---- per-cw-edge: walk cell's CSR neighbors, accumulate 16-dim mean + self feats + mask,
// scatter-add into per-well accumulator. 8 lanes per edge (2 feats per lane).
// wacc[w][0..15]=sum(mask_c*meanx_c), [16..31]=sum(x_c), [32]=sum(mask_c), [33]=edge count.
__global__ __launch_bounds__(256) void k_welledge(const void* __restrict__ xr,
                                                  const int* __restrict__ flag,
                                                  const int* __restrict__ ews,
                                                  const int* __restrict__ ewd,
                                                  const int* __restrict__ offs,
                                                  const int* __restrict__ sorted,
                                                  float* __restrict__ wacc)
{
    int gt = blockIdx.x * 256 + threadIdx.x;
    int e = gt >> 3, jl = gt & 7;
    if (e >= E_CW) return;
    int bf = flag[0];
    unsigned c = (unsigned)ews[e]; if (c >= N_CELL) c = 0;
    unsigned w = (unsigned)ewd[e]; if (w >= N_WELL) w = 0;
    int beg = offs[c], end = offs[c + 1];
    if (beg < 0) beg = 0;
    if (end > E_CC) end = E_CC;
    int deg = end - beg;
    if (deg < 0) deg = 0;
    if (deg > 1024) deg = 1024;       // sanity cap (true max deg ~30)
    float a0 = 0.f, a1 = 0.f, r0, r1;
    if (bf) {
        const unsigned int* x32 = (const unsigned int*)xr;
        unsigned int v = x32[(size_t)c * 8 + jl];
        r0 = lo16(v); r1 = hi16(v);
        for (int j = 0; j < deg; ++j) {
            unsigned s = (unsigned)sorted[beg + j]; if (s >= N_CELL) s = 0;
            unsigned int u = x32[(size_t)s * 8 + jl];
            a0 += lo16(u); a1 += hi16(u);
        }
    } else {
        const float* xf = (const float*)xr;
        r0 = xf[(size_t)c * 16 + 2 * jl]; r1 = xf[(size_t)c * 16 + 2 * jl + 1];
        for (int j = 0; j < deg; ++j) {
            unsigned s = (unsigned)sorted[beg + j]; if (s >= N_CELL) s = 0;
            a0 += xf[(size_t)s * 16 + 2 * jl];
            a1 += xf[(size_t)s * 16 + 2 * jl + 1];
        }
    }
    float sc = (deg > 0) ? (1.0f / (float)deg) : 0.0f;
    float* wr = wacc + (size_t)w * WACC_S;
    atomicAdd(&wr[2 * jl],      a0 * sc);
    atomicAdd(&wr[2 * jl + 1],  a1 * sc);
    atomicAdd(&wr[16 + 2 * jl], r0);
    atomicAdd(&wr[17 + 2 * jl], r1);
    if (jl == 0) {
        atomicAdd(&wr[32], (deg > 0) ? 1.0f : 0.0f);
        atomicAdd(&wr[33], 1.0f);
    }
}

// ---- per-well head: fused SAGE(cw) + MLP. One 128-thread block per well.
__global__ __launch_bounds__(128) void k_wellhead(const float* __restrict__ wacc,
                                                  const int* __restrict__ flag,
                                                  const void* __restrict__ wx,
                                                  const float* __restrict__ G1, const float* __restrict__ G2,
                                                  const float* __restrict__ g1v, const float* __restrict__ g2v,
                                                  const void* __restrict__ W_well,
                                                  const void* __restrict__ b_well,
                                                  const void* __restrict__ Wl_cw,
                                                  const void* __restrict__ bl_cw,
                                                  const void* __restrict__ Wr_cw,
                                                  const void* __restrict__ Wm1,
                                                  const void* __restrict__ bm1,
                                                  const void* __restrict__ Wm2,
                                                  const void* __restrict__ bm2,
                                                  void* __restrict__ outp)
{
    __shared__ float su[34], sa[H], sh0[H], sh1[H], sh2[H];
    int w = blockIdx.x, f = threadIdx.x, bf = flag[0];
    const float* wr = wacc + (size_t)w * WACC_S;
    float cnt = wr[33];
    float inv = (cnt > 0.f) ? (1.0f / cnt) : 0.f;
    if (f < 33) su[f] = wr[f] * inv;
    if (f == 33) su[33] = (cnt > 0.f) ? 1.f : 0.f;
    __syncthreads();
    float mask = su[33], q = su[32];
    float aggw = q * g1v[f] + g2v[f];
#pragma unroll
    for (int k = 0; k < 16; ++k)
        aggw += su[k] * G1[k * H + f] + su[16 + k] * G2[k * H + f];
    aggw *= mask;
    float h0 = ldf(b_well, f, bf);
#pragma unroll
    for (int k = 0; k < WF; ++k)
        h0 += ldf(wx, w * WF + k, bf) * ldf(W_well, k * H + f, bf);
    sa[f] = aggw; sh0[f] = h0;
    __syncthreads();
    float wh = ldf(bl_cw, f, bf);
    for (int k = 0; k < H; ++k)
        wh += sa[k] * ldf(Wl_cw, k * H + f, bf) + sh0[k] * ldf(Wr_cw, k * H + f, bf);
    sh1[f] = wh;
    __syncthreads();
    float m1 = ldf(bm1, f, bf);
    for (int k = 0; k < H; ++k) m1 += sh1[k] * ldf(Wm1, k * H + f, bf);
    sh2[f] = fmaxf(m1, 0.f);
    __syncthreads();
    if (f < OUTF) {
        float o = ldf(bm2, f, bf);
        for (int k = 0; k < H; ++k) o += sh2[k] * ldf(Wm2, k * OUTF + f, bf);
        if (bf) ((unsigned short*)outp)[(size_t)w * OUTF + f] = f2b(o);
        else    ((float*)outp)[(size_t)w * OUTF + f] = o;
    }
}

extern "C" void kernel_launch(void* const* d_in, const int* in_sizes, int n_in,
                              void* d_out, int out_size, void* d_ws, size_t ws_size,
                              hipStream_t stream)
{
    const void* cell_x = d_in[0];
    const void* well_x = d_in[1];
    const int* eic = (const int*)d_in[2];          // [2, E_CC]: row0 = src, row1 = dst
    const int* ews = (const int*)d_in[3];
    const int* ewd = (const int*)d_in[4];
    const void* W_cell = d_in[5];
    const void* b_cell = d_in[6];
    const void* W_well = d_in[7];
    const void* b_well = d_in[8];
    const void* Wl_cc = d_in[9];
    const void* bl_cc = d_in[10];
    const void* Wr_cc = d_in[11];
    const void* Wl_cw = d_in[12];
    const void* bl_cw = d_in[13];
    const void* Wr_cw = d_in[14];
    const void* W_m1 = d_in[15];
    const void* b_m1 = d_in[16];
    const void* W_m2 = d_in[17];
    const void* b_m2 = d_in[18];
    (void)in_sizes; (void)n_in; (void)out_size; (void)ws_size;

    // ---- workspace carve (256B aligned); total ~8.34 MB ----
    char* wsp = (char*)d_ws;
    size_t off = 0;
    auto carve = [&](size_t bytes) -> char* {
        char* p = wsp + off;
        off = (off + bytes + 255) & ~(size_t)255;
        return p;
    };
    float* G1     = (float*)carve(16 * H * 4);
    float* G2     = (float*)carve(16 * H * 4);
    float* g1v    = (float*)carve(H * 4);
    float* g2v    = (float*)carve(H * 4);
    int*   flag   = (int*)carve(256);
    int*   counts = (int*)carve((size_t)N_CELL * 4);            // 800000 (256-divisible)
    float* wacc   = (float*)carve((size_t)N_WELL * WACC_S * 4); // 320000, contiguous after counts
    int*   incl   = (int*)carve((size_t)(NBLK_C * 1024) * 4);
    int*   offs   = (int*)carve((size_t)(N_CELL + 1) * 4);
    int*   curs   = (int*)carve((size_t)(N_CELL + 1) * 4);
    int*   bs     = (int*)carve(256 * 4);
    int*   sorted = (int*)carve((size_t)E_CC * 4);

    const int* cc_src = eic;
    const int* cc_dst = eic + E_CC;

    // 0. dtype sniff (bf16 vs f32)
    k_sniff<<<1, 256, 0, stream>>>((const unsigned int*)cell_x, flag);

    // 1. zero counts + wacc (contiguous) and fused weights
    hipMemsetAsync(counts, 0, (size_t)N_CELL * 4 + (size_t)N_WELL * WACC_S * 4, stream);
    k_precomp<<<17, 128, 0, stream>>>(W_cell, b_cell, Wl_cc, Wr_cc, bl_cc, flag, G1, G2, g1v, g2v);

    // 2. cell CSR build
    k_count<<<(E_CC + 255) / 256, 256, 0, stream>>>(cc_dst, counts);
    k_scan1<<<NBLK_C, 1024, 0, stream>>>(counts, incl, bs);
    k_scan2<<<1, 256, 0, stream>>>(bs);
    k_scan3<<<NBLK_C, 1024, 0, stream>>>(incl, bs, offs, curs);
    k_fill<<<(E_CC + 255) / 256, 256, 0, stream>>>(cc_src, cc_dst, curs, sorted);

    // 3. per-cw-edge two-level aggregation, scatter into per-well sums
    k_welledge<<<(E_CW * 8 + 255) / 256, 256, 0, stream>>>(cell_x, flag, ews, ewd, offs, sorted, wacc);

    // 4. per-well fused head
    k_wellhead<<<N_WELL, 128, 0, stream>>>(wacc, flag, well_x, G1, G2, g1v, g2v,
                                           W_well, b_well, Wl_cw, bl_cw, Wr_cw,
                                           W_m1, b_m1, W_m2, b_m2, d_out);
}